// Round 9
// baseline (865.832 us; speedup 1.0000x reference)
//
#include <hip/hip_runtime.h>
#include <hip/hip_bf16.h>

// ECLGCNN: ChebConv(K=3) on 49152 disjoint 32-node graphs -> per-sample BN ->
// sigmoid -> LSTM(48 steps, H=512) -> linear head. Inputs fp32, output fp32.
// R16: resubmit of R15 (container-level failure, no bench data; kernel
// re-audited deadlock-free: flag DAG is t-monotone, 256 blocks x 86KB LDS =
// 1/CU co-resident as R13/R14). One fix: flag counters back to ONE per 128B
// line (R15 used 64B -> 2 counters/line, the R8 contention class).
// Design: barrier-free LSTM step. W0/W1/W2 fully LDS-resident (84KB, staged
// once); A-operands (X tile + h panel) loaded DIRECTLY global->VGPR as MFMA
// fragments (16B/lane, full 64B lines) -- zero per-step barriers. Each wave =
// independent 16-row x 16-u agent; per-(t,row-chunk) lo/hi counters sync 32
// producer waves -> consumers; 8 free-running waves/CU hide MALL latency.
// Sync protocol otherwise R9-proven (relaxed adds after vmcnt drain, 1-lane
// poll+sleep(4), 2B WT h stores, fresh h slabs).

#define B_    1024
#define T_    48
#define NPG_  32
#define F_    5
#define H_    512
#define EPG_  256
#define NG_   (B_*T_)          // 49152 graphs
#define N_    (B_*T_*NPG_)     // 1572864 nodes
#define E_    (B_*T_*EPG_)     // 12582912 edges
#define NF_   (N_*F_)          // 7864320

typedef __bf16 bf16x8 __attribute__((ext_vector_type(8)));
typedef float  f32x4  __attribute__((ext_vector_type(4)));
typedef __hip_bfloat16 bf16;

__device__ __forceinline__ float sigm(float x)   { return 1.0f/(1.0f+__expf(-x)); }
__device__ __forceinline__ float tanh_f(float x) { return 2.0f/(1.0f+__expf(-2.0f*x)) - 1.0f; }

__device__ __forceinline__ void gl_lds16(const void* g, void* l) {
    __builtin_amdgcn_global_load_lds((const __attribute__((address_space(1))) unsigned int*)g,
                                     (__attribute__((address_space(3))) unsigned int*)l, 16, 0, 0);
}

// write-through bf16 store: coherent at agent scope (MALL), no local-L2 dirty line
__device__ __forceinline__ void store_h_wt(bf16* p, float v) {
    bf16 b = __float2bfloat16(v);
    unsigned short us; __builtin_memcpy(&us, &b, 2);
    __hip_atomic_store(reinterpret_cast<unsigned short*>(p), us,
                       __ATOMIC_RELAXED, __HIP_MEMORY_SCOPE_AGENT);
}

__global__ __launch_bounds__(256) void k_zero(float4* p, int n) {
    int i = blockIdx.x*256 + threadIdx.x;
    if (i < n) p[i] = make_float4(0.f, 0.f, 0.f, 0.f);
}

// Pack W' = [Wih | Whh] row-major [2048][672], fp32 -> bf16. Blocks 0-9 also
// zero bn_acc (k_graph atomic-accumulates BN partials into it).
__global__ __launch_bounds__(256) void k_pack(const float* __restrict__ Wih,
                                              const float* __restrict__ Whh,
                                              bf16* __restrict__ Wp,
                                              float* __restrict__ bn_acc) {
    int i = blockIdx.x*256 + threadIdx.x;           // < 2048*672
    if (blockIdx.x < 10) bn_acc[blockIdx.x*256 + threadIdx.x] = 0.f;
    int r = i / 672, c = i - r*672;
    float v = (c < 160) ? Wih[r*160 + c] : Whh[r*512 + (c-160)];
    Wp[i] = __float2bfloat16(v);
}

// Graph-per-wave ChebConv: 4 graphs per 256-thread block.
__global__ __launch_bounds__(256) void k_graph(
    const float* __restrict__ x, const float* __restrict__ ea,
    const float* __restrict__ cW, const float* __restrict__ cb,
    const int* __restrict__ ei, float* __restrict__ y_pre,
    float* __restrict__ bn_acc)
{
    const int tid = threadIdx.x, w = tid >> 6, lane = tid & 63;
    const int g = blockIdx.x*4 + w;
    __shared__ float Msh[4][1056];                  // Mt[d][s], row stride 33
    __shared__ float dinv[4][32];
    __shared__ float T0s[4][160], T1s[4][160], T2s[4][160];
    __shared__ __align__(16) float Spad[4][256];    // scaled vec, rows padded to 8
    __shared__ float Wsh[75], bsh[5];
    float* mt = Msh[w];

    if (lane < 75) Wsh[lane] = cW[lane];
    if (lane < 5)  bsh[lane] = cb[lane];
    const float4 ew = *reinterpret_cast<const float4*>(ea + (size_t)g*256 + lane*4);
    const int4   es = *reinterpret_cast<const int4*>(ei + (size_t)g*256 + lane*4);
    const int4   ed = *reinterpret_cast<const int4*>(ei + (size_t)E_ + (size_t)g*256 + lane*4);
    T0s[w][lane]      = x[(size_t)g*160 + lane];
    T0s[w][64+lane]   = x[(size_t)g*160 + 64 + lane];
    if (lane < 32) T0s[w][128+lane] = x[(size_t)g*160 + 128 + lane];
    for (int i = lane; i < 1056; i += 64) mt[i] = 0.f;
    __syncthreads();
    atomicAdd(&mt[(ed.x & 31)*33 + (es.x & 31)], ew.x);
    atomicAdd(&mt[(ed.y & 31)*33 + (es.y & 31)], ew.y);
    atomicAdd(&mt[(ed.z & 31)*33 + (es.z & 31)], ew.z);
    atomicAdd(&mt[(ed.w & 31)*33 + (es.w & 31)], ew.w);
    __syncthreads();
    {                                               // deg[s] = sum_d Mt[d][s], 64-lane
        const int s = lane & 31, hh = lane >> 5;
        float dg = 0.f;
        #pragma unroll
        for (int k = 0; k < 16; ++k) dg += mt[(hh*16 + k)*33 + s];
        dg += __shfl_xor(dg, 32, 64);
        if (lane < 32) dinv[w][lane] = dg > 0.f ? rsqrtf(dg) : 0.f;
    }
    __syncthreads();
    for (int i = lane; i < 160; i += 64) Spad[w][(i/5)*8 + (i%5)] = dinv[w][i/5]*T0s[w][i];
    __syncthreads();
    {                                               // T1 = -dinv .* (Mt @ S0), 64-lane
        const int d = lane & 31, hh = lane >> 5;
        float a0=0.f,a1=0.f,a2=0.f,a3=0.f,a4=0.f;
        #pragma unroll 4
        for (int s2 = 0; s2 < 16; ++s2) {
            const int s = s2*2 + hh;
            const float m = mt[d*33+s];
            const float4 sv = *reinterpret_cast<const float4*>(&Spad[w][s*8]);
            const float s4 = Spad[w][s*8+4];
            a0 += m*sv.x; a1 += m*sv.y; a2 += m*sv.z; a3 += m*sv.w; a4 += m*s4;
        }
        a0 += __shfl_xor(a0, 32, 64); a1 += __shfl_xor(a1, 32, 64);
        a2 += __shfl_xor(a2, 32, 64); a3 += __shfl_xor(a3, 32, 64);
        a4 += __shfl_xor(a4, 32, 64);
        if (lane < 32) {
            const float sc = -dinv[w][d];
            T1s[w][d*5+0]=sc*a0; T1s[w][d*5+1]=sc*a1; T1s[w][d*5+2]=sc*a2;
            T1s[w][d*5+3]=sc*a3; T1s[w][d*5+4]=sc*a4;
        }
    }
    __syncthreads();
    for (int i = lane; i < 160; i += 64) Spad[w][(i/5)*8 + (i%5)] = dinv[w][i/5]*T1s[w][i];
    __syncthreads();
    {                                               // T2 = 2 L~ T1 - T0, 64-lane
        const int d = lane & 31, hh = lane >> 5;
        float a0=0.f,a1=0.f,a2=0.f,a3=0.f,a4=0.f;
        #pragma unroll 4
        for (int s2 = 0; s2 < 16; ++s2) {
            const int s = s2*2 + hh;
            const float m = mt[d*33+s];
            const float4 sv = *reinterpret_cast<const float4*>(&Spad[w][s*8]);
            const float s4 = Spad[w][s*8+4];
            a0 += m*sv.x; a1 += m*sv.y; a2 += m*sv.z; a3 += m*sv.w; a4 += m*s4;
        }
        a0 += __shfl_xor(a0, 32, 64); a1 += __shfl_xor(a1, 32, 64);
        a2 += __shfl_xor(a2, 32, 64); a3 += __shfl_xor(a3, 32, 64);
        a4 += __shfl_xor(a4, 32, 64);
        if (lane < 32) {
            const float sc = -2.f*dinv[w][d];
            T2s[w][d*5+0]=sc*a0-T0s[w][d*5+0]; T2s[w][d*5+1]=sc*a1-T0s[w][d*5+1];
            T2s[w][d*5+2]=sc*a2-T0s[w][d*5+2]; T2s[w][d*5+3]=sc*a3-T0s[w][d*5+3];
            T2s[w][d*5+4]=sc*a4-T0s[w][d*5+4];
        }
    }
    __syncthreads();
    float* vb = mt;                                 // reuse adjacency LDS for y
    for (int i = lane; i < 160; i += 64) {
        const int n = i/5, f = i - 5*n;
        float v = bsh[f];
        #pragma unroll
        for (int c = 0; c < 5; ++c)
            v += T0s[w][n*5+c]*Wsh[c*5+f] + T1s[w][n*5+c]*Wsh[25+c*5+f] + T2s[w][n*5+c]*Wsh[50+c*5+f];
        y_pre[(size_t)g*160 + i] = v;
        vb[i] = v;
    }
    __syncthreads();
    {                                               // BN partials -> bn_acc (atomic)
        const int f = lane % 5, cs = (lane/5) & 3;
        const bool sq = lane >= 20;
        float sm = 0.f;
        if (lane < 40) {
            #pragma unroll
            for (int k = 0; k < 8; ++k) { float v = vb[(cs*8+k)*5+f]; sm += sq ? v*v : v; }
        }
        sm += __shfl_down(sm, 5, 64);
        sm += __shfl_down(sm, 10, 64);
        if (lane < 40 && cs == 0)
            atomicAdd(&bn_acc[(size_t)(g/T_)*10 + f + (sq?5:0)], sm);
    }
}

__global__ __launch_bounds__(256) void k_bn(
    const float* __restrict__ y_pre, const float* __restrict__ bn_acc,
    const float* __restrict__ gamma, const float* __restrict__ beta,
    bf16* __restrict__ X)
{
    const int i = blockIdx.x*256 + threadIdx.x;
    const int b   = i / 7680;
    const int rem = i - b*7680;
    const int t   = rem / 160;
    const int pf  = rem - t*160;
    const int f   = pf % 5;
    const float inv  = 1.0f/1536.0f;
    const float mean = bn_acc[b*10+f]*inv;
    const float var  = bn_acc[b*10+5+f]*inv - mean*mean;
    const float v = gamma[f]*(y_pre[i]-mean)*rsqrtf(var+1e-5f) + beta[f];
    X[((size_t)t*B_ + b)*160 + pf] = __float2bfloat16(sigm(v));
}

// ---- barrier-free W-resident persistent LSTM ----
// 256 blocks x 512 thr (8 waves), 1 block/CU, LDS 84KB = W0 20K + W1 32K +
// W2 32K staged once (block's 16 gate-output rows x 4 gates, xor-swizzled).
// Each wave owns 16 batch rows x 16 u: A-fragments loaded global->VGPR
// (lane reads 16B at row(lane&15), k-quad(lane>>4) -- matches mfma A layout;
// full 64B lines per (row,kk)). Per step per wave: issue 5 X-loads, poll lo
// counter, issue 8 h-lo loads, poll hi, issue 8 h-hi loads, 84 MFMAs
// (in-order vmcnt overlaps X-MFMAs with h-loads), epilogue, vmcnt(0) drain,
// relaxed add to (t, chunk=mi*8+w) lo/hi counter (EACH ON ITS OWN 128B LINE).
// NO __syncthreads in the t-loop; 8 waves/CU free-run at different phases.

__device__ __forceinline__ void stage_W512(const char* Wbase, char* lds,
                                           int gpr, int xmask, int ntot, int tid, int u0) {
    for (int p = 0; p*512 < ntot; ++p) {
        const int S = p*512 + tid;
        if (S < ntot) {
            const int row = S / gpr;
            const int col = (S - row*gpr) ^ (row & xmask);
            const int wrow = ((row >> 4) << 9) + u0 + (row & 15);
            gl_lds16(Wbase + (size_t)wrow*1344 + (size_t)col*16, lds + (size_t)S*16);
        }
    }
}

#define CNT_HI_OFF 98304   // (48*64) counters x 32 ints each

__global__ __launch_bounds__(512, 1) void k_lstm(
    const bf16* __restrict__ X,  const bf16* __restrict__ Wp,
    const float* __restrict__ bih, const float* __restrict__ bhh,
    bf16* __restrict__ h_all, float* __restrict__ c_buf,
    int* __restrict__ cnt)
{
    extern __shared__ char sm[];
    char* W0l = sm;                 // 20480
    char* W1l = sm + 20480;         // 32768
    char* W2l = sm + 53248;         // 32768  (total 86016)
    const int tid = threadIdx.x;
    const int lane = tid & 63, w = tid >> 6;
    const int lo = lane & 15, quad = lane >> 4;
    const int arow = w*16 + lo;     // A row within 128-row tile
    const char* Wb = (const char*)Wp;
    const int ui = blockIdx.x & 31;
    const int u0 = ui*16;

    // stage resident W0/W1/W2 once (depend only on ui, invariant per block)
    stage_W512(Wb,       W0l, 20, 3, 1280, tid, u0);
    stage_W512(Wb + 320, W1l, 32, 7, 2048, tid, u0);
    stage_W512(Wb + 832, W2l, 32, 7, 2048, tid, u0);
    const int u = u0 + lo;
    const float bI = bih[u]      + bhh[u];
    const float bF = bih[512+u]  + bhh[512+u];
    const float bG = bih[1024+u] + bhh[1024+u];
    const float bO = bih[1536+u] + bhh[1536+u];
    __syncthreads();                 // W resident; only barrier in the kernel

    for (int t = 0; t < T_; ++t) {
        const char* Hin = (const char*)(h_all + (size_t)t*B_*H_);
        bf16* h_out = h_all + (size_t)(t+1)*B_*H_;
        for (int tile = blockIdx.x; tile < 256; tile += gridDim.x) {
            const int mi = tile >> 5;
            const int m0 = mi*128;
            const int ch = mi*8 + w;           // this wave's row-chunk id
            f32x4 acc[4] = {};

            // X A-fragments direct to VGPR (h-independent; overlaps polls)
            const char* Xr = (const char*)X + (size_t)t*B_*320
                             + (size_t)(m0 + arow)*320 + quad*16;
            bf16x8 xa[5];
            #pragma unroll
            for (int kk = 0; kk < 5; ++kk)
                xa[kk] = *reinterpret_cast<const bf16x8*>(Xr + kk*64);

            // wait lo producers (ui'<16) of step t-1
            if (t > 0 && lane == 0) {
                int* lpc = cnt + (size_t)((t-1)*64 + ch)*32;
                while (__hip_atomic_load(lpc, __ATOMIC_RELAXED,
                                         __HIP_MEMORY_SCOPE_AGENT) < 16)
                    __builtin_amdgcn_s_sleep(4);
            }
            asm volatile("" ::: "memory");
            const char* Hr = Hin + (size_t)(m0 + arow)*1024 + quad*16;
            bf16x8 ha[8];
            #pragma unroll
            for (int kk = 0; kk < 8; ++kk)
                ha[kk] = *reinterpret_cast<const bf16x8*>(Hr + kk*64);
            // wait hi producers (ui'>=16)
            if (t > 0 && lane == 0) {
                int* hpc = cnt + (size_t)((t-1)*64 + ch)*32 + CNT_HI_OFF;
                while (__hip_atomic_load(hpc, __ATOMIC_RELAXED,
                                         __HIP_MEMORY_SCOPE_AGENT) < 16)
                    __builtin_amdgcn_s_sleep(4);
            }
            asm volatile("" ::: "memory");
            bf16x8 hb[8];
            #pragma unroll
            for (int kk = 0; kk < 8; ++kk)
                hb[kk] = *reinterpret_cast<const bf16x8*>(Hr + 512 + kk*64);

            // MFMAs: B-fragments from resident LDS (xor-swizzled layout)
            #pragma unroll
            for (int kk = 0; kk < 5; ++kk) {
                const int kq = kk*4 + quad;
                #pragma unroll
                for (int g = 0; g < 4; ++g) {
                    const int wr = g*16 + lo;
                    const bf16x8 b = *reinterpret_cast<const bf16x8*>(
                        W0l + ((size_t)wr*20 + (kq ^ (wr & 3)))*16);
                    acc[g] = __builtin_amdgcn_mfma_f32_16x16x32_bf16(xa[kk], b, acc[g], 0, 0, 0);
                }
            }
            #pragma unroll
            for (int kk = 0; kk < 8; ++kk) {
                const int kq = kk*4 + quad;
                #pragma unroll
                for (int g = 0; g < 4; ++g) {
                    const int wr = g*16 + lo;
                    const bf16x8 b = *reinterpret_cast<const bf16x8*>(
                        W1l + ((size_t)wr*32 + (kq ^ (wr & 7)))*16);
                    acc[g] = __builtin_amdgcn_mfma_f32_16x16x32_bf16(ha[kk], b, acc[g], 0, 0, 0);
                }
            }
            #pragma unroll
            for (int kk = 0; kk < 8; ++kk) {
                const int kq = kk*4 + quad;
                #pragma unroll
                for (int g = 0; g < 4; ++g) {
                    const int wr = g*16 + lo;
                    const bf16x8 b = *reinterpret_cast<const bf16x8*>(
                        W2l + ((size_t)wr*32 + (kq ^ (wr & 7)))*16);
                    acc[g] = __builtin_amdgcn_mfma_f32_16x16x32_bf16(hb[kk], b, acc[g], 0, 0, 0);
                }
            }

            #pragma unroll
            for (int r = 0; r < 4; ++r) {
                const int m = m0 + w*16 + quad*4 + r;
                const int idx = m*512 + u;
                const float iv = acc[0][r] + bI;
                const float fv = acc[1][r] + bF;
                const float gv = acc[2][r] + bG;
                const float ov = acc[3][r] + bO;
                const float c_new = sigm(fv)*c_buf[idx] + sigm(iv)*tanh_f(gv);
                c_buf[idx] = c_new;
                store_h_wt(&h_out[idx], sigm(ov)*tanh_f(c_new));
            }
            asm volatile("s_waitcnt vmcnt(0)" ::: "memory");  // h at MALL
            if (lane == 0) {                     // per-wave flag: relaxed add
                int* pc = cnt + (size_t)(t*64 + ch)*32 + (ui < 16 ? 0 : CNT_HI_OFF);
                __hip_atomic_fetch_add(pc, 1, __ATOMIC_RELAXED,
                                       __HIP_MEMORY_SCOPE_AGENT);
            }
        }
    }
}

// out[b,j] = sigmoid( sum_{t,u} sigm(h[t,b,u]) * lin_W[j, t*512+u] + lin_b[j] )
__global__ __launch_bounds__(256) void k_final(
    const bf16* __restrict__ hs, const float* __restrict__ lW,
    const float* __restrict__ lb, float* __restrict__ out)
{
    const int b = blockIdx.x, tid = threadIdx.x;
    const int u = tid*2;
    float a0=0.f, a1=0.f, a2=0.f, a3=0.f;
    for (int t = 0; t < T_; ++t) {
        const bf16* hr = hs + ((size_t)t*B_ + b)*H_ + u;
        const float h0 = sigm((float)hr[0]), h1 = sigm((float)hr[1]);
        const int o = t*H_ + u;
        a0 += h0*lW[o]         + h1*lW[o+1];
        a1 += h0*lW[24576+o]   + h1*lW[24576+o+1];
        a2 += h0*lW[49152+o]   + h1*lW[49152+o+1];
        a3 += h0*lW[73728+o]   + h1*lW[73728+o+1];
    }
    #pragma unroll
    for (int off = 32; off > 0; off >>= 1) {
        a0 += __shfl_down(a0, off, 64);
        a1 += __shfl_down(a1, off, 64);
        a2 += __shfl_down(a2, off, 64);
        a3 += __shfl_down(a3, off, 64);
    }
    __shared__ float red[4][4];
    const int wave = tid >> 6, lane = tid & 63;
    if (lane == 0) { red[0][wave]=a0; red[1][wave]=a1; red[2][wave]=a2; red[3][wave]=a3; }
    __syncthreads();
    if (tid < 4) {
        float s = red[tid][0]+red[tid][1]+red[tid][2]+red[tid][3] + lb[tid];
        out[b*4 + tid] = sigm(s);
    }
}

extern "C" void kernel_launch(void* const* d_in, const int* in_sizes, int n_in,
                              void* d_out, int out_size, void* d_ws, size_t ws_size,
                              hipStream_t stream) {
    const float* x   = (const float*)d_in[0];
    const float* ea  = (const float*)d_in[1];
    const float* cW  = (const float*)d_in[2];
    const float* cb  = (const float*)d_in[3];
    const float* gam = (const float*)d_in[4];
    const float* bet = (const float*)d_in[5];
    const float* Wih = (const float*)d_in[6];
    const float* Whh = (const float*)d_in[7];
    const float* bih = (const float*)d_in[8];
    const float* bhh = (const float*)d_in[9];
    const float* lW  = (const float*)d_in[10];
    const float* lb  = (const float*)d_in[11];
    const int*   ei  = (const int*)d_in[12];
    float* out = (float*)d_out;

    // Workspace (~72.8 MB):
    // [bn_acc 40KB][Wp 2.75MB][X 15.7MB][big 51.8MB]
    // big phase 1: y_pre @0 (31.5MB)
    // big phase 2: cnt @0 (768KB: (48x64) lo + hi counters, 128B-padded),
    //              c @768KB (2MB), h_all @768KB+2MB (49 x 1MB)
    char* ws = (char*)d_ws;
    float* bn_acc = (float*)ws;
    bf16*  Wp     = (bf16*)(ws + 40960);
    bf16*  X      = (bf16*)(ws + 2793472);
    char*  big    = ws + 18522112;
    float* y_pre  = (float*)big;
    int*   cnt    = (int*)big;
    float* c_buf  = (float*)(big + 786432);
    bf16*  h_all  = (bf16*)(big + 786432 + 2097152);

    (void)hipFuncSetAttribute((const void*)k_lstm,
                              hipFuncAttributeMaxDynamicSharedMemorySize, 86016);

    static int nblk = 0;                 // persistent grid: 1 block/CU
    if (nblk == 0) {
        int dev = 0, ncu = 0;
        if (hipGetDevice(&dev) != hipSuccess) dev = 0;
        if (hipDeviceGetAttribute(&ncu, hipDeviceAttributeMultiprocessorCount, dev)
                != hipSuccess || ncu <= 0) ncu = 256;
        nblk = ncu; if (nblk > 256) nblk = 256;
        nblk = (nblk/32)*32; if (nblk < 32) nblk = 32;  // keep ui invariant per block
    }

    k_pack<<<5376, 256, 0, stream>>>(Wih, Whh, Wp, bn_acc);
    k_graph<<<NG_/4, 256, 0, stream>>>(x, ea, cW, cb, ei, y_pre, bn_acc);
    k_bn<<<NF_/256, 256, 0, stream>>>(y_pre, bn_acc, gam, bet, X);
    // zero cnt (768KB) + c (2MB) + h_all slab 0 (1MB) = 245760 float4
    k_zero<<<960, 256, 0, stream>>>((float4*)big, 245760);
    k_lstm<<<nblk, 512, 86016, stream>>>(X, Wp, bih, bhh, h_all, c_buf, cnt);
    k_final<<<B_, 256, 0, stream>>>(h_all + (size_t)B_*H_, lW, lb, out);
}

// Round 10
// 707.767 us; speedup vs baseline: 1.2233x; 1.2233x over previous
//
#include <hip/hip_runtime.h>
#include <hip/hip_bf16.h>

// ECLGCNN: ChebConv(K=3) on 49152 disjoint 32-node graphs -> per-sample BN ->
// sigmoid -> LSTM(48 steps, H=512) -> linear head. Inputs fp32, output fp32.
// R17: k_lstm reverted to R14-exact (best measured: 384us; R15/R16 barrier-
// free variant was register-starved, VGPR=64 -> serialized MALL latency).
// k_graph: the 4 waves of a block process 4 INDEPENDENT graphs (all LDS is
// [w]-indexed) -- the 9 __syncthreads were pure convoy. Replaced with wave-
// local fences (s_waitcnt lgkmcnt(0) + memory clobber; lockstep lanes make
// this sufficient for cross-lane LDS RAW). Wsh/bsh made per-wave (each wave
// copies all 75 weights -- also closes the lane<75 writer gap).

#define B_    1024
#define T_    48
#define NPG_  32
#define F_    5
#define H_    512
#define EPG_  256
#define NG_   (B_*T_)          // 49152 graphs
#define N_    (B_*T_*NPG_)     // 1572864 nodes
#define E_    (B_*T_*EPG_)     // 12582912 edges
#define NF_   (N_*F_)          // 7864320

typedef __bf16 bf16x8 __attribute__((ext_vector_type(8)));
typedef float  f32x4  __attribute__((ext_vector_type(4)));
typedef __hip_bfloat16 bf16;

__device__ __forceinline__ float sigm(float x)   { return 1.0f/(1.0f+__expf(-x)); }
__device__ __forceinline__ float tanh_f(float x) { return 2.0f/(1.0f+__expf(-2.0f*x)) - 1.0f; }

__device__ __forceinline__ void gl_lds16(const void* g, void* l) {
    __builtin_amdgcn_global_load_lds((const __attribute__((address_space(1))) unsigned int*)g,
                                     (__attribute__((address_space(3))) unsigned int*)l, 16, 0, 0);
}

// write-through bf16 store: coherent at agent scope (MALL), no local-L2 dirty line
__device__ __forceinline__ void store_h_wt(bf16* p, float v) {
    bf16 b = __float2bfloat16(v);
    unsigned short us; __builtin_memcpy(&us, &b, 2);
    __hip_atomic_store(reinterpret_cast<unsigned short*>(p), us,
                       __ATOMIC_RELAXED, __HIP_MEMORY_SCOPE_AGENT);
}

// wave-local LDS fence: all prior LDS ops by this wave complete; lanes are
// lockstep so this orders cross-lane LDS RAW within the wave.
__device__ __forceinline__ void wave_fence() {
    asm volatile("s_waitcnt lgkmcnt(0)" ::: "memory");
}

__global__ __launch_bounds__(256) void k_zero(float4* p, int n) {
    int i = blockIdx.x*256 + threadIdx.x;
    if (i < n) p[i] = make_float4(0.f, 0.f, 0.f, 0.f);
}

// Pack W' = [Wih | Whh] row-major [2048][672], fp32 -> bf16. Blocks 0-9 also
// zero bn_acc (k_graph atomic-accumulates BN partials into it).
__global__ __launch_bounds__(256) void k_pack(const float* __restrict__ Wih,
                                              const float* __restrict__ Whh,
                                              bf16* __restrict__ Wp,
                                              float* __restrict__ bn_acc) {
    int i = blockIdx.x*256 + threadIdx.x;           // < 2048*672
    if (blockIdx.x < 10) bn_acc[blockIdx.x*256 + threadIdx.x] = 0.f;
    int r = i / 672, c = i - r*672;
    float v = (c < 160) ? Wih[r*160 + c] : Whh[r*512 + (c-160)];
    Wp[i] = __float2bfloat16(v);
}

// Graph-per-wave ChebConv: 4 graphs per 256-thread block, waves free-running
// (zero __syncthreads; wave-local fences only).
__global__ __launch_bounds__(256) void k_graph(
    const float* __restrict__ x, const float* __restrict__ ea,
    const float* __restrict__ cW, const float* __restrict__ cb,
    const int* __restrict__ ei, float* __restrict__ y_pre,
    float* __restrict__ bn_acc)
{
    const int tid = threadIdx.x, w = tid >> 6, lane = tid & 63;
    const int g = blockIdx.x*4 + w;
    __shared__ float Msh[4][1056];                  // Mt[d][s], row stride 33
    __shared__ float dinv[4][32];
    __shared__ float T0s[4][160], T1s[4][160], T2s[4][160];
    __shared__ __align__(16) float Spad[4][256];    // scaled vec, rows padded to 8
    __shared__ float Wsh[4][80], bsh[4][8];         // per-wave (no cross-wave dep)
    float* mt = Msh[w];

    for (int i = lane; i < 75; i += 64) Wsh[w][i] = cW[i];
    if (lane < 5) bsh[w][lane] = cb[lane];
    const float4 ew = *reinterpret_cast<const float4*>(ea + (size_t)g*256 + lane*4);
    const int4   es = *reinterpret_cast<const int4*>(ei + (size_t)g*256 + lane*4);
    const int4   ed = *reinterpret_cast<const int4*>(ei + (size_t)E_ + (size_t)g*256 + lane*4);
    T0s[w][lane]      = x[(size_t)g*160 + lane];
    T0s[w][64+lane]   = x[(size_t)g*160 + 64 + lane];
    if (lane < 32) T0s[w][128+lane] = x[(size_t)g*160 + 128 + lane];
    for (int i = lane; i < 1056; i += 64) mt[i] = 0.f;
    wave_fence();
    atomicAdd(&mt[(ed.x & 31)*33 + (es.x & 31)], ew.x);
    atomicAdd(&mt[(ed.y & 31)*33 + (es.y & 31)], ew.y);
    atomicAdd(&mt[(ed.z & 31)*33 + (es.z & 31)], ew.z);
    atomicAdd(&mt[(ed.w & 31)*33 + (es.w & 31)], ew.w);
    wave_fence();
    {                                               // deg[s] = sum_d Mt[d][s], 64-lane
        const int s = lane & 31, hh = lane >> 5;
        float dg = 0.f;
        #pragma unroll
        for (int k = 0; k < 16; ++k) dg += mt[(hh*16 + k)*33 + s];
        dg += __shfl_xor(dg, 32, 64);
        if (lane < 32) dinv[w][lane] = dg > 0.f ? rsqrtf(dg) : 0.f;
    }
    wave_fence();
    for (int i = lane; i < 160; i += 64) Spad[w][(i/5)*8 + (i%5)] = dinv[w][i/5]*T0s[w][i];
    wave_fence();
    {                                               // T1 = -dinv .* (Mt @ S0), 64-lane
        const int d = lane & 31, hh = lane >> 5;
        float a0=0.f,a1=0.f,a2=0.f,a3=0.f,a4=0.f;
        #pragma unroll 4
        for (int s2 = 0; s2 < 16; ++s2) {
            const int s = s2*2 + hh;
            const float m = mt[d*33+s];
            const float4 sv = *reinterpret_cast<const float4*>(&Spad[w][s*8]);
            const float s4 = Spad[w][s*8+4];
            a0 += m*sv.x; a1 += m*sv.y; a2 += m*sv.z; a3 += m*sv.w; a4 += m*s4;
        }
        a0 += __shfl_xor(a0, 32, 64); a1 += __shfl_xor(a1, 32, 64);
        a2 += __shfl_xor(a2, 32, 64); a3 += __shfl_xor(a3, 32, 64);
        a4 += __shfl_xor(a4, 32, 64);
        if (lane < 32) {
            const float sc = -dinv[w][d];
            T1s[w][d*5+0]=sc*a0; T1s[w][d*5+1]=sc*a1; T1s[w][d*5+2]=sc*a2;
            T1s[w][d*5+3]=sc*a3; T1s[w][d*5+4]=sc*a4;
        }
    }
    wave_fence();
    for (int i = lane; i < 160; i += 64) Spad[w][(i/5)*8 + (i%5)] = dinv[w][i/5]*T1s[w][i];
    wave_fence();
    {                                               // T2 = 2 L~ T1 - T0, 64-lane
        const int d = lane & 31, hh = lane >> 5;
        float a0=0.f,a1=0.f,a2=0.f,a3=0.f,a4=0.f;
        #pragma unroll 4
        for (int s2 = 0; s2 < 16; ++s2) {
            const int s = s2*2 + hh;
            const float m = mt[d*33+s];
            const float4 sv = *reinterpret_cast<const float4*>(&Spad[w][s*8]);
            const float s4 = Spad[w][s*8+4];
            a0 += m*sv.x; a1 += m*sv.y; a2 += m*sv.z; a3 += m*sv.w; a4 += m*s4;
        }
        a0 += __shfl_xor(a0, 32, 64); a1 += __shfl_xor(a1, 32, 64);
        a2 += __shfl_xor(a2, 32, 64); a3 += __shfl_xor(a3, 32, 64);
        a4 += __shfl_xor(a4, 32, 64);
        if (lane < 32) {
            const float sc = -2.f*dinv[w][d];
            T2s[w][d*5+0]=sc*a0-T0s[w][d*5+0]; T2s[w][d*5+1]=sc*a1-T0s[w][d*5+1];
            T2s[w][d*5+2]=sc*a2-T0s[w][d*5+2]; T2s[w][d*5+3]=sc*a3-T0s[w][d*5+3];
            T2s[w][d*5+4]=sc*a4-T0s[w][d*5+4];
        }
    }
    wave_fence();
    float* vb = mt;                                 // reuse adjacency LDS for y
    for (int i = lane; i < 160; i += 64) {
        const int n = i/5, f = i - 5*n;
        float v = bsh[w][f];
        #pragma unroll
        for (int c = 0; c < 5; ++c)
            v += T0s[w][n*5+c]*Wsh[w][c*5+f] + T1s[w][n*5+c]*Wsh[w][25+c*5+f] + T2s[w][n*5+c]*Wsh[w][50+c*5+f];
        y_pre[(size_t)g*160 + i] = v;
        vb[i] = v;
    }
    wave_fence();
    {                                               // BN partials -> bn_acc (atomic)
        const int f = lane % 5, cs = (lane/5) & 3;
        const bool sq = lane >= 20;
        float sm = 0.f;
        if (lane < 40) {
            #pragma unroll
            for (int k = 0; k < 8; ++k) { float v = vb[(cs*8+k)*5+f]; sm += sq ? v*v : v; }
        }
        sm += __shfl_down(sm, 5, 64);
        sm += __shfl_down(sm, 10, 64);
        if (lane < 40 && cs == 0)
            atomicAdd(&bn_acc[(size_t)(g/T_)*10 + f + (sq?5:0)], sm);
    }
}

__global__ __launch_bounds__(256) void k_bn(
    const float* __restrict__ y_pre, const float* __restrict__ bn_acc,
    const float* __restrict__ gamma, const float* __restrict__ beta,
    bf16* __restrict__ X)
{
    const int i = blockIdx.x*256 + threadIdx.x;
    const int b   = i / 7680;
    const int rem = i - b*7680;
    const int t   = rem / 160;
    const int pf  = rem - t*160;
    const int f   = pf % 5;
    const float inv  = 1.0f/1536.0f;
    const float mean = bn_acc[b*10+f]*inv;
    const float var  = bn_acc[b*10+5+f]*inv - mean*mean;
    const float v = gamma[f]*(y_pre[i]-mean)*rsqrtf(var+1e-5f) + beta[f];
    X[((size_t)t*B_ + b)*160 + pf] = __float2bfloat16(sigm(v));
}

// ---- W-resident persistent LSTM (128KB LDS, per-producer flag lines) ----
// R14-exact (best measured). 256 tiles (8 m-groups x 32 u-tiles), tile =
// 128 batch rows x 64 gate rows. 512-thread blocks (8 waves), 1 block/CU.
// LDS 131072: A-buf 64KB (P0: X 40KB + W0 20KB; P1/P2: h halves 64KB),
// W1/W2 32KB each staged ONCE. Flags: flag[t][mi][ui] on its own 128B line;
// producer = relaxed agent STORE after vmcnt drain; consumer = wave0 lanes
// 0-15 poll distinct lines + s_sleep(4). P1 waits ui<16; ui>=16 poll
// overlaps h-lo staging issue.

__device__ __forceinline__ void stage_A512(const char* gbase, int strideB, char* lds,
                                           int gpr, int xmask, int nper, int tid) {
    for (int p = 0; p < nper; ++p) {
        const int S = p*512 + tid;
        const int row = S / gpr;
        const int col = (S - row*gpr) ^ (row & xmask);
        gl_lds16(gbase + (size_t)row*strideB + (size_t)col*16, lds + (size_t)S*16);
    }
}

__device__ __forceinline__ void stage_W512(const char* Wbase, char* lds,
                                           int gpr, int xmask, int ntot, int tid, int u0) {
    for (int p = 0; p*512 < ntot; ++p) {
        const int S = p*512 + tid;
        if (S < ntot) {
            const int row = S / gpr;
            const int col = (S - row*gpr) ^ (row & xmask);
            const int wrow = ((row >> 4) << 9) + u0 + (row & 15);
            gl_lds16(Wbase + (size_t)wrow*1344 + (size_t)col*16, lds + (size_t)S*16);
        }
    }
}

__device__ __forceinline__ void mfma_phase(const char* Al, const char* Wl, int gpr,
                                           int xmask, int nkk, int arow, int lo,
                                           int quad, f32x4 acc[4]) {
    for (int kk = 0; kk < nkk; ++kk) {
        const int kq = kk*4 + quad;
        const bf16x8 a = *reinterpret_cast<const bf16x8*>(
            Al + ((size_t)arow*gpr + (kq ^ (arow & xmask)))*16);
        #pragma unroll
        for (int g = 0; g < 4; ++g) {
            const int wr = g*16 + lo;
            const bf16x8 b = *reinterpret_cast<const bf16x8*>(
                Wl + ((size_t)wr*gpr + (kq ^ (wr & xmask)))*16);
            acc[g] = __builtin_amdgcn_mfma_f32_16x16x32_bf16(a, b, acc[g], 0, 0, 0);
        }
    }
}

// poll 16 flags (one per lane, distinct 128B lines)
__device__ __forceinline__ void poll16(const int* base, int lane) {
    const int* p = base + (size_t)lane*32;
    while (__hip_atomic_load(p, __ATOMIC_RELAXED, __HIP_MEMORY_SCOPE_AGENT) == 0)
        __builtin_amdgcn_s_sleep(4);
}

__global__ __launch_bounds__(512, 1) void k_lstm(
    const bf16* __restrict__ X,  const bf16* __restrict__ Wp,
    const float* __restrict__ bih, const float* __restrict__ bhh,
    bf16* __restrict__ h_all, float* __restrict__ c_buf,
    int* __restrict__ cnt)
{
    extern __shared__ char sm[];
    char* Al  = sm;                 // 65536 (P0: X@0 40960 + W0@40960 20480)
    char* W1l = sm + 65536;         // 32768
    char* W2l = sm + 98304;         // 32768
    const int tid = threadIdx.x;
    const int lane = tid & 63, w = tid >> 6;
    const int lo = lane & 15, quad = lane >> 4;
    const int arow = w*16 + lo;     // A row within 128-row tile
    const char* Wb = (const char*)Wp;
    const int ui = blockIdx.x & 31;
    const int u0 = ui*16;

    // stage resident W1/W2 once (depend only on ui, invariant per block)
    stage_W512(Wb + 320, W1l, 32, 7, 2048, tid, u0);
    stage_W512(Wb + 832, W2l, 32, 7, 2048, tid, u0);
    const int u = u0 + lo;
    const float bI = bih[u]      + bhh[u];
    const float bF = bih[512+u]  + bhh[512+u];
    const float bG = bih[1024+u] + bhh[1024+u];
    const float bO = bih[1536+u] + bhh[1536+u];

    for (int t = 0; t < T_; ++t) {
        const char* Hin = (const char*)(h_all + (size_t)t*B_*H_);
        bf16* h_out = h_all + (size_t)(t+1)*B_*H_;
        for (int tile = blockIdx.x; tile < 256; tile += gridDim.x) {
            const int mi = tile >> 5;
            const int m0 = mi*128;
            const char* Xb = (const char*)X + (size_t)t*B_*320 + (size_t)m0*320;
            const char* Hb = Hin + (size_t)m0*1024;
            const int* fprev = cnt + (size_t)((t-1)*8 + mi)*32*32;
            f32x4 acc[4] = {};

            // phase 0: X part (K=160) -- h-independent
            stage_A512(Xb, 320, Al, 20, 3, 5, tid);          // X tile 40KB
            stage_W512(Wb, Al + 40960, 20, 3, 1280, tid, u0); // W0 20KB (L2-hot)
            __syncthreads();                          // drains vmcnt: LDS ready
            mfma_phase(Al, Al + 40960, 20, 3, 5, arow, lo, quad, acc);
            if (t > 0 && w == 0 && lane < 16)         // wait lo producers (ui<16)
                poll16(fprev, lane);
            __syncthreads();
            // phase 1: h[0:256) -- needs lo producers only
            stage_A512(Hb, 1024, Al, 32, 7, 8, tid);
            if (t > 0 && w == 0 && lane < 16)         // hi poll overlaps staging
                poll16(fprev + 16*32, lane);
            __syncthreads();                          // drains vmcnt + joins poll
            mfma_phase(Al, W1l, 32, 7, 8, arow, lo, quad, acc);
            __syncthreads();
            // phase 2: h[256:512) -- hi producers confirmed above
            stage_A512(Hb + 512, 1024, Al, 32, 7, 8, tid);
            __syncthreads();
            mfma_phase(Al, W2l, 32, 7, 8, arow, lo, quad, acc);

            #pragma unroll
            for (int r = 0; r < 4; ++r) {
                const int m = m0 + w*16 + quad*4 + r;
                const int idx = m*512 + u;
                const float iv = acc[0][r] + bI;
                const float fv = acc[1][r] + bF;
                const float gv = acc[2][r] + bG;
                const float ov = acc[3][r] + bO;
                const float c_new = sigm(fv)*c_buf[idx] + sigm(iv)*tanh_f(gv);
                c_buf[idx] = c_new;
                store_h_wt(&h_out[idx], sigm(ov)*tanh_f(c_new));
            }
            __syncthreads();                          // drains vmcnt: h at MALL
            if (tid == 0)                             // own line: parallel at MALL
                __hip_atomic_store(cnt + (size_t)((t*8 + mi)*32 + ui)*32, 1,
                                   __ATOMIC_RELAXED, __HIP_MEMORY_SCOPE_AGENT);
        }
    }
}

// out[b,j] = sigmoid( sum_{t,u} sigm(h[t,b,u]) * lin_W[j, t*512+u] + lin_b[j] )
__global__ __launch_bounds__(256) void k_final(
    const bf16* __restrict__ hs, const float* __restrict__ lW,
    const float* __restrict__ lb, float* __restrict__ out)
{
    const int b = blockIdx.x, tid = threadIdx.x;
    const int u = tid*2;
    float a0=0.f, a1=0.f, a2=0.f, a3=0.f;
    for (int t = 0; t < T_; ++t) {
        const bf16* hr = hs + ((size_t)t*B_ + b)*H_ + u;
        const float h0 = sigm((float)hr[0]), h1 = sigm((float)hr[1]);
        const int o = t*H_ + u;
        a0 += h0*lW[o]         + h1*lW[o+1];
        a1 += h0*lW[24576+o]   + h1*lW[24576+o+1];
        a2 += h0*lW[49152+o]   + h1*lW[49152+o+1];
        a3 += h0*lW[73728+o]   + h1*lW[73728+o+1];
    }
    #pragma unroll
    for (int off = 32; off > 0; off >>= 1) {
        a0 += __shfl_down(a0, off, 64);
        a1 += __shfl_down(a1, off, 64);
        a2 += __shfl_down(a2, off, 64);
        a3 += __shfl_down(a3, off, 64);
    }
    __shared__ float red[4][4];
    const int wave = tid >> 6, lane = tid & 63;
    if (lane == 0) { red[0][wave]=a0; red[1][wave]=a1; red[2][wave]=a2; red[3][wave]=a3; }
    __syncthreads();
    if (tid < 4) {
        float s = red[tid][0]+red[tid][1]+red[tid][2]+red[tid][3] + lb[tid];
        out[b*4 + tid] = sigm(s);
    }
}

extern "C" void kernel_launch(void* const* d_in, const int* in_sizes, int n_in,
                              void* d_out, int out_size, void* d_ws, size_t ws_size,
                              hipStream_t stream) {
    const float* x   = (const float*)d_in[0];
    const float* ea  = (const float*)d_in[1];
    const float* cW  = (const float*)d_in[2];
    const float* cb  = (const float*)d_in[3];
    const float* gam = (const float*)d_in[4];
    const float* bet = (const float*)d_in[5];
    const float* Wih = (const float*)d_in[6];
    const float* Whh = (const float*)d_in[7];
    const float* bih = (const float*)d_in[8];
    const float* bhh = (const float*)d_in[9];
    const float* lW  = (const float*)d_in[10];
    const float* lb  = (const float*)d_in[11];
    const int*   ei  = (const int*)d_in[12];
    float* out = (float*)d_out;

    // Workspace (~70.2 MB):
    // [bn_acc 40KB][Wp 2.75MB][X 15.7MB][big 52.5MB]
    // big phase 1: y_pre @0 (31.5MB)
    // big phase 2: flags @0 (1.5MB: 48x8x32 x 128B lines),
    //              c @1.5MB (2MB), h_all @3.5MB (49 x 1MB)
    char* ws = (char*)d_ws;
    float* bn_acc = (float*)ws;
    bf16*  Wp     = (bf16*)(ws + 40960);
    bf16*  X      = (bf16*)(ws + 2793472);
    char*  big    = ws + 18522112;
    float* y_pre  = (float*)big;
    int*   cnt    = (int*)big;
    float* c_buf  = (float*)(big + 1572864);
    bf16*  h_all  = (bf16*)(big + 1572864 + 2097152);

    (void)hipFuncSetAttribute((const void*)k_lstm,
                              hipFuncAttributeMaxDynamicSharedMemorySize, 131072);

    static int nblk = 0;                 // persistent grid: 1 block/CU (128KB LDS)
    if (nblk == 0) {
        int dev = 0, ncu = 0;
        if (hipGetDevice(&dev) != hipSuccess) dev = 0;
        if (hipDeviceGetAttribute(&ncu, hipDeviceAttributeMultiprocessorCount, dev)
                != hipSuccess || ncu <= 0) ncu = 256;
        nblk = ncu; if (nblk > 256) nblk = 256;
        nblk = (nblk/32)*32; if (nblk < 32) nblk = 32;  // keep ui invariant per block
    }

    k_pack<<<5376, 256, 0, stream>>>(Wih, Whh, Wp, bn_acc);
    k_graph<<<NG_/4, 256, 0, stream>>>(x, ea, cW, cb, ei, y_pre, bn_acc);
    k_bn<<<NF_/256, 256, 0, stream>>>(y_pre, bn_acc, gam, bet, X);
    // zero flags (1.5MB) + c (2MB) + h_all slab 0 (1MB) = 294912 float4
    k_zero<<<1152, 256, 0, stream>>>((float4*)big, 294912);
    k_lstm<<<nblk, 512, 131072, stream>>>(X, Wp, bih, bhh, h_all, c_buf, cnt);
    k_final<<<B_, 256, 0, stream>>>(h_all + (size_t)B_*H_, lW, lb, out);
}